// Round 12
// baseline (760.998 us; speedup 1.0000x reference)
//
#include <hip/hip_runtime.h>

#define B_ 32
#define N_ 4096
#define ENC_ 1024
#define DEC_ 512
#define ATT_ 512
#define ROWSTR 1040   // bytes per 64-row LDS row: 512 bf16 + 16B pad (2-way-free banks)

typedef __attribute__((ext_vector_type(8))) short short8;
typedef __attribute__((ext_vector_type(4))) float f32x4;
typedef __attribute__((ext_vector_type(4))) unsigned u32x4;

__device__ __forceinline__ short f2bf(float f) {
  union { float f; unsigned u; } x; x.f = f;
  unsigned r = (x.u + 0x7FFFu + ((x.u >> 16) & 1u)) >> 16;
  return (short)r;
}
__device__ __forceinline__ unsigned cvtpk(float a, float b) {
  unsigned r;
  asm("v_cvt_pk_bf16_f32 %0, %1, %2" : "=v"(r) : "v"(a), "v"(b));
  return r;
}
__device__ __forceinline__ void lds_barrier() {
  asm volatile("s_waitcnt lgkmcnt(0)" ::: "memory");
  __builtin_amdgcn_s_barrier();
  asm volatile("" ::: "memory");
}

// ---------------------------------------------------------------------------
// Kernel 1: att2 prep + W_enc -> bf16 fragment-ordered Wfrag (unchanged).
// Wfrag[((cf*32+g)*64+l)*8+j] = W_enc[g*32+(l>>4)*8+j][cf*16+(l&15)]
// ---------------------------------------------------------------------------
extern "C" __global__ void __launch_bounds__(256) prep_kernel(
    const float* __restrict__ dh, const float* __restrict__ W_dec,
    const float* __restrict__ b_dec, const float* __restrict__ b_enc,
    const float* __restrict__ W_enc,
    float* __restrict__ att2, short* __restrict__ Wfrag)
{
  if (blockIdx.x < B_) {
    __shared__ float dhs[DEC_];
    int b = blockIdx.x;
    for (int i = threadIdx.x; i < DEC_; i += 256) dhs[i] = dh[b * DEC_ + i];
    __syncthreads();
    for (int a = threadIdx.x; a < ATT_; a += 256) {
      float s = b_dec[a] + b_enc[a];
      for (int k = 0; k < DEC_; ++k) s += dhs[k] * W_dec[k * ATT_ + a];
      att2[b * ATT_ + a] = s;
    }
  } else {
    int idx = (blockIdx.x - B_) * 256 + threadIdx.x;
    int l = idx & 63;
    int g = (idx >> 6) & 31;
    int c = idx >> 11;
    int col = c * 16 + (l & 15);
    int kb = g * 32 + (l >> 4) * 8;
    short8 p;
#pragma unroll
    for (int j = 0; j < 8; ++j) p[j] = f2bf(W_enc[(kb + j) * ATT_ + col]);
    *(short8*)(Wfrag + ((long)idx << 3)) = p;
  }
}

// ---------------------------------------------------------------------------
// Kernel 2: fused  e[b,n] = sum_a relu((enc@W_enc)[n,a] + att2[b,a]) * w[a]
// PERSISTENT blocks: 256 blocks x 512 thr (8 waves), each does 8 sequential
// 64-row x 512-col tiles (full K per tile -- relu forbids K-split).
// A: staged per tile in TWO half-K pieces (64x512 bf16, padded-stride LDS,
//    ping-pong As[0]=h0 / As[1]=h1): 16 contiguous f32x4 loads/thread issued
//    MID-COMPUTE of the previous half (~2500cyc in flight), cvt_pk + 8x
//    ds_write_b128 late, lgkm-only barrier. 2 barriers/tile (was 16-32).
// B: register double-buffer per K=32 chunk from L2-resident Wfrag.
// ---------------------------------------------------------------------------
extern "C" __global__ void __launch_bounds__(512, 2) gemm_e_kernel(
    const float* __restrict__ enc, const short* __restrict__ Wfrag,
    const float* __restrict__ att2, const float* __restrict__ w_full,
    float* __restrict__ e_out)
{
  __shared__ __align__(16) short As[2][64 * (ROWSTR / 2)];  // 66.5 KB each
  __shared__ float e_red[64][8];

  const int tid = threadIdx.x;
  const int lane = tid & 63;
  const int w = tid >> 6;              // wave 0..7 -> cols w*64..
  const int blk = blockIdx.x;          // 256 persistent blocks
  const int b = blk >> 3;              // 8 tiles/block, 64 tiles/batch

  // staging coords: thread -> (row = tid>>3, 256B segment = tid&7)
  const int srow = tid >> 3;
  const int sseg = tid & 7;
  const int awb = srow * ROWSTR + sseg * 128;   // LDS byte base (linear+pad)
  const float* apRun = enc + ((long)(blk * 512 + srow)) * ENC_ + sseg * 64;

  // A fragment read byte bases: row rr = r*16+(lane&15), +c*64 per chunk
  int arb[4];
#pragma unroll
  for (int r = 0; r < 4; ++r)
    arb[r] = (r * 16 + (lane & 15)) * ROWSTR + (lane >> 4) * 16;

  // B: col-frag cf = w*4+cc, chunk g at Wfrag[(cf*32+g)*512 + lane*8]
  const short* bptr = Wfrag + (long)(w * 4) * 16384 + lane * 8;

  // epilogue constants (b fixed per block)
  const int lq = lane >> 4, lr = lane & 15;
  float at2v[4], wv[4];
#pragma unroll
  for (int c = 0; c < 4; ++c) {
    int col = w * 64 + c * 16 + lr;
    at2v[c] = att2[b * ATT_ + col];
    wv[c] = w_full[col];
  }

  f32x4 pA[16];

#define ISSUE_A(PTR)                                                          \
  {                                                                           \
    _Pragma("unroll")                                                         \
    for (int j = 0; j < 16; ++j) pA[j] = *(const f32x4*)((PTR) + j * 4);      \
  }

#define CVT_WRITE(BUF)                                                        \
  {                                                                           \
    _Pragma("unroll")                                                         \
    for (int u = 0; u < 8; ++u) {                                             \
      union { u32x4 uu; short8 ss; } q;                                       \
      q.uu[0] = cvtpk(pA[2 * u][0], pA[2 * u][1]);                            \
      q.uu[1] = cvtpk(pA[2 * u][2], pA[2 * u][3]);                            \
      q.uu[2] = cvtpk(pA[2 * u + 1][0], pA[2 * u + 1][1]);                    \
      q.uu[3] = cvtpk(pA[2 * u + 1][2], pA[2 * u + 1][3]);                    \
      *(short8*)((char*)&As[BUF][0] + awb + u * 16) = q.ss;                   \
    }                                                                         \
  }

  // COMPUTE over 16 chunks from As[BUF]; B chunks g0..g0+15; optionally
  // issues next A-half's 16 loads at chunk 8 (after that chunk's B issue).
#define COMPUTE(BUF, G0, DO_ISSUE, APTR)                                      \
  {                                                                           \
    short8 Bb[2][4];                                                          \
    _Pragma("unroll")                                                         \
    for (int cc = 0; cc < 4; ++cc)                                            \
      Bb[0][cc] = *(const short8*)(bptr + cc * 16384 + (G0) * 512);           \
    _Pragma("unroll")                                                         \
    for (int c = 0; c < 16; ++c) {                                            \
      const int cb = c & 1, nb = cb ^ 1;                                      \
      if (c < 15) {                                                           \
        _Pragma("unroll")                                                     \
        for (int cc = 0; cc < 4; ++cc)                                        \
          Bb[nb][cc] =                                                        \
              *(const short8*)(bptr + cc * 16384 + ((G0) + c + 1) * 512);     \
      }                                                                       \
      __builtin_amdgcn_sched_barrier(0);                                      \
      if (c == 8 && (DO_ISSUE)) { ISSUE_A(APTR); }                            \
      __builtin_amdgcn_sched_barrier(0);                                      \
      short8 af[4];                                                           \
      _Pragma("unroll")                                                       \
      for (int r = 0; r < 4; ++r)                                             \
        af[r] = *(const short8*)((const char*)&As[BUF][0] + arb[r] + c * 64); \
      __builtin_amdgcn_s_setprio(1);                                          \
      _Pragma("unroll")                                                       \
      for (int cc = 0; cc < 4; ++cc) {                                        \
        _Pragma("unroll")                                                     \
        for (int r = 0; r < 4; ++r)                                           \
          acc[r][cc] = __builtin_amdgcn_mfma_f32_16x16x32_bf16(               \
              af[r], Bb[cb][cc], acc[r][cc], 0, 0, 0);                        \
      }                                                                       \
      __builtin_amdgcn_s_setprio(0);                                          \
    }                                                                         \
  }

  // ---- prologue: stage tile0 half0 into As[0]
  ISSUE_A(apRun);
  CVT_WRITE(0);
  lds_barrier();

  // ---- persistent tile loop (NOT unrolled: keep I-cache small)
#pragma unroll 1
  for (int i = 0; i < 8; ++i) {
    f32x4 acc[4][4] = {};

    // half 0: compute As[0] (g 0..15); mid-issue A(i, h1)
    COMPUTE(0, 0, 1, apRun + 512);
    CVT_WRITE(1);
    lds_barrier();

    // half 1: compute As[1] (g 16..31); mid-issue A(i+1, h0)
    const int more = (i < 7);
    COMPUTE(1, 16, more, apRun + 65536);
    if (more) CVT_WRITE(0);

    // ---- epilogue for tile i (its __syncthreads also publishes As[0])
#pragma unroll
    for (int r = 0; r < 4; ++r) {
#pragma unroll
      for (int j = 0; j < 4; ++j) {
        float s = 0.f;
#pragma unroll
        for (int c = 0; c < 4; ++c)
          s += fmaxf(acc[r][c][j] + at2v[c], 0.f) * wv[c];
        s += __shfl_xor(s, 1); s += __shfl_xor(s, 2);
        s += __shfl_xor(s, 4); s += __shfl_xor(s, 8);
        if (lr == 0) e_red[r * 16 + lq * 4 + j][w] = s;
      }
    }
    __syncthreads();
    if (tid < 64) {
      float ev = 0.f;
#pragma unroll
      for (int ww = 0; ww < 8; ++ww) ev += e_red[tid][ww];
      int ti = blk * 8 + i;
      e_out[b * N_ + (ti & 63) * 64 + tid] = ev;
    }
    apRun += 65536;   // next 64-row tile
  }
#undef COMPUTE
#undef CVT_WRITE
#undef ISSUE_A
}

// ---------------------------------------------------------------------------
// Kernel 3: softmax over N per batch (single e plane).
// ---------------------------------------------------------------------------
extern "C" __global__ void __launch_bounds__(256) softmax_kernel(
    const float* __restrict__ e, float* __restrict__ alpha)
{
  int b = blockIdx.x, tid = threadIdx.x;
  float v[16];
  float m = -1e30f;
#pragma unroll
  for (int i = 0; i < 16; ++i) {
    v[i] = e[b * N_ + i * 256 + tid];
    m = fmaxf(m, v[i]);
  }
  for (int off = 1; off < 64; off <<= 1) m = fmaxf(m, __shfl_xor(m, off));
  __shared__ float redm[4];
  if ((tid & 63) == 0) redm[tid >> 6] = m;
  __syncthreads();
  m = fmaxf(fmaxf(redm[0], redm[1]), fmaxf(redm[2], redm[3]));
  float s = 0.f;
#pragma unroll
  for (int i = 0; i < 16; ++i) { v[i] = expf(v[i] - m); s += v[i]; }
  for (int off = 1; off < 64; off <<= 1) s += __shfl_xor(s, off);
  __shared__ float reds[4];
  if ((tid & 63) == 0) reds[tid >> 6] = s;
  __syncthreads();
  s = reds[0] + reds[1] + reds[2] + reds[3];
  float inv = 1.0f / s;
#pragma unroll
  for (int i = 0; i < 16; ++i) alpha[b * N_ + i * 256 + tid] = v[i] * inv;
}

// ---------------------------------------------------------------------------
// Kernel 4: partial awe. grid = b(32) x cchunk(4) x nchunk(16)
// ---------------------------------------------------------------------------
extern "C" __global__ void __launch_bounds__(256) awe_part_kernel(
    const float* __restrict__ enc, const float* __restrict__ alpha,
    float* __restrict__ part)
{
  __shared__ float als[256];
  __shared__ f32x4 red[256];
  int bi = blockIdx.x;
  int b = bi & 31, cchunk = (bi >> 5) & 3, nchunk = bi >> 7;
  int t = threadIdx.x;
  int n0 = nchunk * 256;
  als[t] = alpha[b * N_ + n0 + t];
  __syncthreads();
  int tcol = t & 63, tn = t >> 6;
  const float* base = enc + (long)b * N_ * ENC_ + (long)n0 * ENC_ +
                      cchunk * 256 + tcol * 4;
  f32x4 acc = {};
  for (int i = tn; i < 256; i += 4) {
    f32x4 vv = *(const f32x4*)(base + (long)i * ENC_);
    acc += als[i] * vv;
  }
  red[t] = acc;
  __syncthreads();
  if (t < 64) {
    f32x4 s = red[t] + red[t + 64] + red[t + 128] + red[t + 192];
    *(f32x4*)(&part[(long)nchunk * 32768 + b * 1024 + cchunk * 256 + t * 4]) = s;
  }
}

// Kernel 5: combine the 16 n-partials
extern "C" __global__ void __launch_bounds__(256) awe_reduce_kernel(
    const float* __restrict__ part, float* __restrict__ awe)
{
  int i = blockIdx.x * 256 + threadIdx.x;
  float s = 0.f;
#pragma unroll
  for (int p = 0; p < 16; ++p) s += part[(long)p * 32768 + i];
  awe[i] = s;
}

// ---------------------------------------------------------------------------
extern "C" void kernel_launch(void* const* d_in, const int* in_sizes, int n_in,
                              void* d_out, int out_size, void* d_ws, size_t ws_size,
                              hipStream_t stream) {
  const float* enc    = (const float*)d_in[0];
  const float* dh     = (const float*)d_in[1];
  const float* W_enc  = (const float*)d_in[2];
  const float* b_enc  = (const float*)d_in[3];
  const float* W_dec  = (const float*)d_in[4];
  const float* b_dec  = (const float*)d_in[5];
  const float* w_full = (const float*)d_in[6];
  // d_in[7] = b_full: softmax shift-invariant, unused.
  float* out = (float*)d_out;   // [awe 32*1024 | alpha 32*4096]

  char* ws = (char*)d_ws;
  float* att2  = (float*)ws;                                  // 64 KB
  short* Wfrag = (short*)(ws + 65536);                        // 1 MB
  float* e_buf = (float*)(ws + 65536 + 1048576);              // 512 KB
  float* part  = (float*)(ws + 65536 + 1048576 + 524288);     // 2 MB

  hipLaunchKernelGGL(prep_kernel, dim3(B_ + 256), dim3(256), 0, stream,
                     dh, W_dec, b_dec, b_enc, W_enc, att2, Wfrag);
  hipLaunchKernelGGL(gemm_e_kernel, dim3(256), dim3(512), 0, stream,
                     enc, Wfrag, att2, w_full, e_buf);
  hipLaunchKernelGGL(softmax_kernel, dim3(B_), dim3(256), 0, stream,
                     e_buf, out + B_ * ENC_);
  hipLaunchKernelGGL(awe_part_kernel, dim3(2048), dim3(256), 0, stream,
                     enc, out + B_ * ENC_, part);
  hipLaunchKernelGGL(awe_reduce_kernel, dim3(128), dim3(256), 0, stream,
                     part, out);
}